// Round 10
// baseline (424.851 us; speedup 1.0000x reference)
//
#include <hip/hip_runtime.h>

#define B_ 128
#define T_ 2048
#define N_ 64
#define L_ 256
#define NSEG 6       // segments per batch
#define SEG  342     // steps per segment (5x64 + 22; renorm every 64)
#define NEGV (-1e30f)
#define PITCH 72     // shorts per LDS row (64 + 8 pad), keeps b128 16B-aligned
#define LOG2E 1.4426950408889634f
#define LN2   0.6931471805599453f

typedef short  s16x8 __attribute__((ext_vector_type(8)));
typedef float  f32x4 __attribute__((ext_vector_type(4)));
typedef unsigned int u32x2 __attribute__((ext_vector_type(2)));

__device__ __forceinline__ short f2bf_rne(float f) {
    unsigned u = __float_as_uint(f);
    unsigned r = (u + 0x7FFFu + ((u >> 16) & 1u)) >> 16;
    return (short)r;
}
__device__ __forceinline__ float bf2f(unsigned short u) {
    return __uint_as_float(((unsigned)u) << 16);
}
__device__ __forceinline__ unsigned pkpair(float lo, float hi) {
    return __builtin_amdgcn_perm(__float_as_uint(hi) + 0x8000u,
                                 __float_as_uint(lo) + 0x8000u, 0x07060302u);
}
__device__ __forceinline__ float bperm(int byteaddr, float v) {
    return __int_as_float(__builtin_amdgcn_ds_bpermute(byteaddr, __float_as_int(v)));
}
// whole-wave DPP shifts: dst[i]=src[i-1] (shr) / dst[i]=src[i+1] (shl);
// invalid boundary lane keeps `old` = NEGV (bound_ctrl=false, masks 0xF)
__device__ __forceinline__ float dpp_wshr1(float src) {
    return __int_as_float(__builtin_amdgcn_update_dpp(
        __float_as_int(NEGV), __float_as_int(src), 0x138, 0xF, 0xF, false));
}
__device__ __forceinline__ float dpp_wshl1(float src) {
    return __int_as_float(__builtin_amdgcn_update_dpp(
        __float_as_int(NEGV), __float_as_int(src), 0x130, 0xF, 0xF, false));
}
__device__ __forceinline__ float lse2b(float p, float q) {
    float mx = fmaxf(p, q);
    float t  = __builtin_amdgcn_exp2f(-fabsf(p - q));
    return mx + __builtin_amdgcn_logf(1.f + t);
}

// Kernel 1: 256 blocks x 256 thr, 1 block/CU. wave0 = fac (fwd blk<128 / bwd);
// waves 1..3 = fcc segment builders (768 waves, 6 segs x 342 steps per batch).
__global__ __launch_bounds__(256, 1) void asg_k1(
    const float* __restrict__ x,       // (B,T,N)
    const int*   __restrict__ target,  // (B,L)
    const int*   __restrict__ tsize,   // (B,)
    const float* __restrict__ trans,   // (N,N)
    float* __restrict__ ws_c,          // (B,6) segment log-scales
    unsigned short* __restrict__ ws_R, // (B,6,64,64) bf16 seg matrices, col-major S[n][m]=P[m][n]
    float* __restrict__ ws_v,          // (B,256) alpha_1023 (log2 domain)
    float* __restrict__ ws_w)          // (B,256) beta_1023  (log2 domain)
{
    __shared__ short lds[3][N_ * PITCH];
    const int blk  = blockIdx.x;
    const int wid  = threadIdx.x >> 6;
    const int lane = threadIdx.x & 63;

    if (wid == 0 && blk < 128) {
        // ---------------- FAC forward: alpha_0 .. alpha_1023 ----------------
        const int b  = blk;
        const float* __restrict__ xb = x + (size_t)b * T_ * N_;
        const int l0 = lane * 4;
        int tga[4]; float slf[4], mv[4], a[4];
        #pragma unroll
        for (int j = 0; j < 4; ++j) {
            const int tv = target[b * L_ + l0 + j];
            tga[j] = tv << 2;
            slf[j] = trans[tv * N_ + tv] * LOG2E;
            if (j > 0) mv[j] = trans[tv * N_ + (target[b * L_ + l0 + j - 1])] * LOG2E;
            a[j] = NEGV;
        }
        const int tR = target[b * L_ + ((l0 - 1 >= 0) ? l0 - 1 : 0)];
        mv[0] = trans[(tga[0] >> 2) * N_ + tR] * LOG2E;
        if (lane == 0) a[0] = xb[tga[0] >> 2] * LOG2E;   // alpha0[0]

        float xr[16];
        #pragma unroll
        for (int i = 0; i < 16; ++i) xr[i] = xb[(size_t)(1 + i) * N_ + lane];
        // emission pipeline, 2 steps deep: E[(i+1)&1] consumed at step slot i
        float E[2][4];
        {
            const float s1 = xr[0] * LOG2E, s2 = xr[1] * LOG2E;
            #pragma unroll
            for (int j = 0; j < 4; ++j) E[1][j] = bperm(tga[j], s1);
            #pragma unroll
            for (int j = 0; j < 4; ++j) E[0][j] = bperm(tga[j], s2);
        }

        #define FWD_STEP(i, rp, RF)                                             \
        {                                                                       \
            const int ei = ((i) + 1) & 1;                                       \
            const float c0 = E[ei][0], c1 = E[ei][1], c2 = E[ei][2], c3 = E[ei][3]; \
            const float scn = xr[((i) + 2) & 15] * LOG2E;                       \
            E[ei][0] = bperm(tga[0], scn); E[ei][1] = bperm(tga[1], scn);       \
            E[ei][2] = bperm(tga[2], scn); E[ei][3] = bperm(tga[3], scn);       \
            if (RF) xr[i] = (rp)[lane];                                         \
            const float up = dpp_wshr1(a[3]);                                   \
            const float n0 = lse2b(a[0] + slf[0], up   + mv[0]) + c0;           \
            const float n1 = lse2b(a[1] + slf[1], a[0] + mv[1]) + c1;           \
            const float n2 = lse2b(a[2] + slf[2], a[1] + mv[2]) + c2;           \
            const float n3 = lse2b(a[3] + slf[3], a[2] + mv[3]) + c3;           \
            a[0] = n0; a[1] = n1; a[2] = n2; a[3] = n3;                         \
        }
        for (int u = 0; u < 63; ++u) {                  // t = 1..1008
            const float* __restrict__ xp = xb + (size_t)(16 * u + 17) * N_;
            #pragma unroll
            for (int i = 0; i < 16; ++i) FWD_STEP(i, xp + i * N_, true);
        }
        #pragma unroll
        for (int i = 0; i < 15; ++i) FWD_STEP(i, xb, false);   // t = 1009..1023
        #undef FWD_STEP
        *(float4*)(ws_v + b * 256 + l0) = make_float4(a[0], a[1], a[2], a[3]);
    } else if (wid == 0) {
        // ---------------- FAC backward: beta_2047 .. beta_1023 ----------------
        const int b  = blk - 128;
        const float* __restrict__ xb = x + (size_t)b * T_ * N_;
        const int l0 = lane * 4;
        const int lt = tsize[b] - 1;
        int tga[4]; float slf[4], mvin[4], a[4];
        #pragma unroll
        for (int j = 0; j < 4; ++j) {
            const int tv = target[b * L_ + l0 + j];
            tga[j] = tv << 2;
            slf[j] = trans[tv * N_ + tv] * LOG2E;
            if (j > 0) mvin[j] = trans[tv * N_ + (target[b * L_ + l0 + j - 1])] * LOG2E;
            a[j] = (l0 + j == lt) ? 0.f : NEGV;
        }
        const int tN = target[b * L_ + ((l0 + 4 <= L_ - 1) ? l0 + 4 : L_ - 1)];
        const float mvR = trans[tN * N_ + (tga[3] >> 2)] * LOG2E;  // move into cell l0+4

        float xr[16];
        #pragma unroll
        for (int i = 0; i < 16; ++i) xr[i] = xb[(size_t)(2047 - i) * N_ + lane];
        float E[2][4];
        {
            const float s1 = xr[0] * LOG2E, s2 = xr[1] * LOG2E;
            #pragma unroll
            for (int j = 0; j < 4; ++j) E[1][j] = bperm(tga[j], s1);
            #pragma unroll
            for (int j = 0; j < 4; ++j) E[0][j] = bperm(tga[j], s2);
        }

        #define BWD_STEP(i, rp, RF)                                             \
        {                                                                       \
            const int ei = ((i) + 1) & 1;                                       \
            const float c0 = E[ei][0], c1 = E[ei][1], c2 = E[ei][2], c3 = E[ei][3]; \
            const float scn = xr[((i) + 2) & 15] * LOG2E;                       \
            E[ei][0] = bperm(tga[0], scn); E[ei][1] = bperm(tga[1], scn);       \
            E[ei][2] = bperm(tga[2], scn); E[ei][3] = bperm(tga[3], scn);       \
            if (RF) xr[i] = (rp)[lane];                                         \
            const float t0v = a[0] + c0, t1v = a[1] + c1,                       \
                        t2v = a[2] + c2, t3v = a[3] + c3;                       \
            const float tsh = dpp_wshl1(t0v);                                   \
            const float n0 = lse2b(t0v + slf[0], t1v + mvin[1]);                \
            const float n1 = lse2b(t1v + slf[1], t2v + mvin[2]);                \
            const float n2 = lse2b(t2v + slf[2], t3v + mvin[3]);                \
            const float n3 = lse2b(t3v + slf[3], tsh + mvR);                    \
            a[0] = n0; a[1] = n1; a[2] = n2; a[3] = n3;                         \
        }
        for (int u = 0; u < 63; ++u) {                  // t = 2047..1040
            const float* __restrict__ xp = xb + (size_t)(2047 - 16 * u - 16) * N_;
            #pragma unroll
            for (int i = 0; i < 16; ++i) BWD_STEP(i, xp - (size_t)i * N_, true);
        }
        #pragma unroll
        for (int i = 0; i < 16; ++i) BWD_STEP(i, xb, false);   // t = 1039..1024
        #undef BWD_STEP
        *(float4*)(ws_w + b * 256 + l0) = make_float4(a[0], a[1], a[2], a[3]);
    } else {
        // ---- FCC segment: P = prod over 342 steps, renorm every 64 ----
        const int w   = blk * 3 + (wid - 1);       // 0..767
        const int b   = w / NSEG, seg = w % NSEG;
        const int c = lane & 15, g = lane >> 4;
        const float* __restrict__ xb = x + (size_t)b * T_ * N_;
        const int t0 = seg * SEG;
        short* __restrict__ myl = lds[wid - 1];

        // A = Ehat (const) + LS
        s16x8 Afrag[4][2];
        float rs[4] = {0.f, 0.f, 0.f, 0.f};
        #pragma unroll
        for (int mt = 0; mt < 4; ++mt)
            #pragma unroll
            for (int kt = 0; kt < 2; ++kt) {
                s16x8 af;
                #pragma unroll
                for (int jj = 0; jj < 8; ++jj) {
                    float v = __expf(trans[(c + 16 * mt) * N_ + 32 * kt + 8 * g + jj]);
                    af[jj] = f2bf_rne(v);
                    rs[mt] += v;
                }
                Afrag[mt][kt] = af;
            }
        #pragma unroll
        for (int mt = 0; mt < 4; ++mt) {
            rs[mt] += __shfl_xor(rs[mt], 16);
            rs[mt] += __shfl_xor(rs[mt], 32);
        }
        float rmax = fmaxf(fmaxf(rs[0], rs[1]), fmaxf(rs[2], rs[3]));
        #pragma unroll
        for (int o = 8; o > 0; o >>= 1) rmax = fmaxf(rmax, __shfl_xor(rmax, o));
        const float LS = __logf(rmax);

        // B = identity (running product, NOT reset between windows)
        s16x8 Bfrag[2][4];
        #pragma unroll
        for (int kt = 0; kt < 2; ++kt)
            #pragma unroll
            for (int nt = 0; nt < 4; ++nt) {
                s16x8 bf;
                #pragma unroll
                for (int jj = 0; jj < 8; ++jj)
                    bf[jj] = (32 * kt + 8 * g + jj == c + 16 * nt) ? (short)0x3F80 : (short)0;
                Bfrag[kt][nt] = bf;
            }

        float4 xr[2][4];
        #pragma unroll
        for (int p = 0; p < 2; ++p)
            #pragma unroll
            for (int tr = 0; tr < 4; ++tr)
                xr[p][tr] = *(const float4*)(xb + (size_t)(t0 + 1 + p) * N_ + 16 * tr + 4 * g);

        float c_acc = 0.f;
        int t = t0 + 1;

        #define CH_STEP(PAR, RN)                                                  \
        {                                                                         \
            f32x4 Cacc[4][4];                                                     \
            _Pragma("unroll")                                                     \
            for (int mt = 0; mt < 4; ++mt)                                        \
                _Pragma("unroll")                                                 \
                for (int nt = 0; nt < 4; ++nt) {                                  \
                    f32x4 z = {0.f, 0.f, 0.f, 0.f};                               \
                    z = __builtin_amdgcn_mfma_f32_16x16x32_bf16(Afrag[mt][0], Bfrag[0][nt], z, 0, 0, 0); \
                    Cacc[mt][nt] = __builtin_amdgcn_mfma_f32_16x16x32_bf16(Afrag[mt][1], Bfrag[1][nt], z, 0, 0, 0); \
                }                                                                 \
            float4 xv[4];                                                         \
            _Pragma("unroll")                                                     \
            for (int tr = 0; tr < 4; ++tr) xv[tr] = xr[PAR][tr];                  \
            int tpre = t + 2; if (tpre > T_ - 1) tpre = T_ - 1;                   \
            _Pragma("unroll")                                                     \
            for (int tr = 0; tr < 4; ++tr)                                        \
                xr[PAR][tr] = *(const float4*)(xb + (size_t)tpre * N_ + 16 * tr + 4 * g); \
            const float gt = __uint_as_float(__builtin_amdgcn_readfirstlane(__float_as_uint(xv[0].x))) + LS; \
            if (t < T_) {                                                         \
                c_acc += gt;                                                      \
                float ev[4][4];                                                   \
                _Pragma("unroll")                                                 \
                for (int tr = 0; tr < 4; ++tr) {                                  \
                    ev[tr][0] = __expf(xv[tr].x - gt);                            \
                    ev[tr][1] = __expf(xv[tr].y - gt);                            \
                    ev[tr][2] = __expf(xv[tr].z - gt);                            \
                    ev[tr][3] = __expf(xv[tr].w - gt);                            \
                }                                                                 \
                _Pragma("unroll")                                                 \
                for (int mt = 0; mt < 4; ++mt)                                    \
                    _Pragma("unroll")                                             \
                    for (int nt = 0; nt < 4; ++nt) {                              \
                        Cacc[mt][nt][0] *= ev[mt][0];                             \
                        Cacc[mt][nt][1] *= ev[mt][1];                             \
                        Cacc[mt][nt][2] *= ev[mt][2];                             \
                        Cacc[mt][nt][3] *= ev[mt][3];                             \
                    }                                                             \
                if (RN) {                                                         \
                    float vm = 0.f;                                               \
                    _Pragma("unroll")                                             \
                    for (int mt = 0; mt < 4; ++mt)                                \
                        _Pragma("unroll")                                         \
                        for (int nt = 0; nt < 4; ++nt)                            \
                            vm = fmaxf(vm, fmaxf(fmaxf(Cacc[mt][nt][0], Cacc[mt][nt][1]), \
                                                 fmaxf(Cacc[mt][nt][2], Cacc[mt][nt][3]))); \
                    _Pragma("unroll")                                             \
                    for (int o = 32; o > 0; o >>= 1) vm = fmaxf(vm, __shfl_xor(vm, o)); \
                    const float scf = __builtin_amdgcn_rcpf(vm);                  \
                    c_acc += __logf(vm);                                          \
                    _Pragma("unroll")                                             \
                    for (int mt = 0; mt < 4; ++mt)                                \
                        _Pragma("unroll")                                         \
                        for (int nt = 0; nt < 4; ++nt) {                          \
                            Cacc[mt][nt][0] *= scf; Cacc[mt][nt][1] *= scf;       \
                            Cacc[mt][nt][2] *= scf; Cacc[mt][nt][3] *= scf;       \
                        }                                                         \
                }                                                                 \
                _Pragma("unroll")                                                 \
                for (int mt = 0; mt < 4; ++mt)                                    \
                    _Pragma("unroll")                                             \
                    for (int nt = 0; nt < 4; ++nt) {                              \
                        u32x2 pk;                                                 \
                        pk[0] = pkpair(Cacc[mt][nt][0], Cacc[mt][nt][1]);         \
                        pk[1] = pkpair(Cacc[mt][nt][2], Cacc[mt][nt][3]);         \
                        *(u32x2*)&myl[(16 * nt + c) * PITCH + 16 * mt + 4 * g] = pk; \
                    }                                                             \
                _Pragma("unroll")                                                 \
                for (int kt = 0; kt < 2; ++kt)                                    \
                    _Pragma("unroll")                                             \
                    for (int nt = 0; nt < 4; ++nt)                                \
                        Bfrag[kt][nt] = *(const s16x8*)&myl[(16 * nt + c) * PITCH + 32 * kt + 8 * g]; \
            }                                                                     \
            ++t;                                                                  \
        }

        for (int sub = 0; sub < 5; ++sub) {            // 5 x 64-step windows
            for (int s2 = 0; s2 < 31; ++s2) { CH_STEP(0, false); CH_STEP(1, false); }
            CH_STEP(0, false); CH_STEP(1, true);       // renorm on window's last step
        }
        for (int s2 = 0; s2 < 11; ++s2) { CH_STEP(0, false); CH_STEP(1, false); } // 22 tail
        #undef CH_STEP

        // store col-major S[n][m] = P[m][n]: straight b128 copy of myl
        unsigned short* dst = ws_R + (size_t)(b * NSEG + seg) * 4096;
        #pragma unroll
        for (int r = 0; r < 8; ++r)
            *(s16x8*)&dst[lane * 64 + r * 8] = *(const s16x8*)&myl[lane * PITCH + r * 8];
        if (lane == 0) ws_c[b * NSEG + seg] = c_acc;
    }
}

// Kernel 2: wave0 = serial combine over 6 segment matrices (LDS dbuf + prefetch;
// row-broadcast matvec on col-major S); wave1 = fac combine. One block per batch.
__global__ __launch_bounds__(128) void asg_k2(
    const float* __restrict__ x,
    const float* __restrict__ ws_c,
    const unsigned short* __restrict__ ws_R,
    const float* __restrict__ ws_v,
    const float* __restrict__ ws_w,
    float* __restrict__ out)
{
    __shared__ short rb[2][N_ * PITCH];
    __shared__ __align__(16) float sa[N_];
    __shared__ float sres[2];
    const int b = blockIdx.x, tid = threadIdx.x;
    const int lane = tid & 63, wv = tid >> 6;

    if (wv == 1) {
        // fac combine: lse over 256 cells of (alpha+beta), log2 in -> ln out
        float4 v4 = ((const float4*)(ws_v + b * 256))[lane];
        float4 w4 = ((const float4*)(ws_w + b * 256))[lane];
        const float s0 = v4.x + w4.x, s1 = v4.y + w4.y,
                    s2 = v4.z + w4.z, s3 = v4.w + w4.w;
        float m = fmaxf(fmaxf(s0, s1), fmaxf(s2, s3));
        #pragma unroll
        for (int o = 32; o > 0; o >>= 1) m = fmaxf(m, __shfl_xor(m, o));
        float sum = __builtin_amdgcn_exp2f(s0 - m) + __builtin_amdgcn_exp2f(s1 - m)
                  + __builtin_amdgcn_exp2f(s2 - m) + __builtin_amdgcn_exp2f(s3 - m);
        #pragma unroll
        for (int o = 32; o > 0; o >>= 1) sum += __shfl_xor(sum, o);
        if (lane == 0) sres[1] = (m + __builtin_amdgcn_logf(sum)) * LN2;
    } else {
        float a0 = x[(size_t)b * T_ * N_ + lane];
        float m0 = a0;
        #pragma unroll
        for (int o = 32; o > 0; o >>= 1) m0 = fmaxf(m0, __shfl_xor(m0, o));
        float  a  = __expf(a0 - m0);
        double Cd = (double)m0;

        const unsigned short* Rb = ws_R + (size_t)b * NSEG * 4096;
        const int srow = lane >> 3, scol = (lane & 7) * 8;
        s16x8 nv[8];
        #pragma unroll
        for (int q = 0; q < 8; ++q)
            nv[q] = *(const s16x8*)(Rb + lane * 8 + 512 * q);
        #pragma unroll
        for (int q = 0; q < 8; ++q)
            *(s16x8*)&rb[0][(srow + 8 * q) * PITCH + scol] = nv[q];
        #pragma unroll
        for (int q = 0; q < 8; ++q)
            nv[q] = *(const s16x8*)(Rb + 4096 + lane * 8 + 512 * q);

        for (int kk = 0; kk < NSEG; ++kk) {
            sa[lane] = a;
            // acc[m=lane] = sum_n S[n][m]*sa[n]; rb[n*PITCH + m] = S[n][m]
            float acc = 0.f;
            #pragma unroll
            for (int nq = 0; nq < 16; ++nq) {
                const float4 sv = ((const float4*)sa)[nq];
                const short* rp = &rb[kk & 1][(nq * 4) * PITCH + lane];
                acc = fmaf(bf2f(*(const unsigned short*)(rp)),             sv.x, acc);
                acc = fmaf(bf2f(*(const unsigned short*)(rp + PITCH)),     sv.y, acc);
                acc = fmaf(bf2f(*(const unsigned short*)(rp + 2 * PITCH)), sv.z, acc);
                acc = fmaf(bf2f(*(const unsigned short*)(rp + 3 * PITCH)), sv.w, acc);
            }
            if (kk + 1 < NSEG) {
                #pragma unroll
                for (int q = 0; q < 8; ++q)
                    *(s16x8*)&rb[(kk + 1) & 1][(srow + 8 * q) * PITCH + scol] = nv[q];
                const int kp = (kk + 2 < NSEG) ? kk + 2 : NSEG - 1;
                #pragma unroll
                for (int q = 0; q < 8; ++q)
                    nv[q] = *(const s16x8*)(Rb + (size_t)kp * 4096 + lane * 8 + 512 * q);
            }
            const float r = bperm(0, acc);   // all-positive; lane0 within e^~15 of max
            a = acc * __builtin_amdgcn_rcpf(r);
            Cd += (double)(__logf(r) + ws_c[b * NSEG + kk]);
        }
        float ssum = a;
        #pragma unroll
        for (int o = 32; o > 0; o >>= 1) ssum += __shfl_xor(ssum, o);
        if (lane == 0) sres[0] = (float)(Cd + (double)__logf(ssum));
    }
    __syncthreads();
    if (tid == 0) out[b] = sres[0] - sres[1];
}

extern "C" void kernel_launch(void* const* d_in, const int* in_sizes, int n_in,
                              void* d_out, int out_size, void* d_ws, size_t ws_size,
                              hipStream_t stream) {
    (void)in_sizes; (void)n_in; (void)out_size; (void)ws_size;
    const float* xin    = (const float*)d_in[0];
    const int*   target = (const int*)  d_in[1];
    const int*   tsz    = (const int*)  d_in[2];
    const float* trans  = (const float*)d_in[3];
    float* out = (float*)d_out;

    float*          ws_c = (float*)d_ws;                                    // 3 KB
    unsigned short* ws_R = (unsigned short*)((char*)d_ws + 16384);          // 6.29 MB
    float*          ws_v = (float*)((char*)d_ws + 16384 + 6291456);         // 128 KB
    float*          ws_w = (float*)((char*)d_ws + 16384 + 6291456 + 131072);

    // 256 blocks, 1/CU: wave0 fac, waves 1..3 = 768 segment waves (6 per batch)
    asg_k1<<<dim3(256), dim3(256), 0, stream>>>(xin, target, tsz, trans,
                                                ws_c, ws_R, ws_v, ws_w);
    asg_k2<<<dim3(B_), dim3(128), 0, stream>>>(xin, ws_c, ws_R, ws_v, ws_w, out);
}